// Round 11
// baseline (15327.679 us; speedup 1.0000x reference)
//
#include <hip/hip_runtime.h>
#include <stdint.h>
#include <math.h>

#define V 30000
#define E 60000
#define G 1200
#define D 64
#define NODE_IN 74
#define EDGE_IN 12
#define EH 128
#define N_MP 6
#define N_S2S 6

#define NBLK ((E + 63) / 64)   // 938 edge-tiles of 64
#define EPAD (NBLK * 64)       // 60032 padded edge rows
#define GRUBLK ((V + 31) / 32) // 938 node-tiles of 32

typedef short bf16x8 __attribute__((ext_vector_type(8)));
typedef float f32x4 __attribute__((ext_vector_type(4)));

__device__ __forceinline__ float sigmoidf_(float x) {
    return 1.0f / (1.0f + __expf(-x));
}
__device__ __forceinline__ float tanhf_(float x) {
    float t = __expf(-2.0f * fabsf(x));
    float r = (1.0f - t) / (1.0f + t);
    return copysignf(r, x);
}
__device__ __forceinline__ uint16_t f2bf(float f) {
    uint32_t u = __float_as_uint(f);
    u += 0x7fffu + ((u >> 16) & 1u);
    return (uint16_t)(u >> 16);
}
__device__ __forceinline__ float bf2f(uint16_t u) {
    return __uint_as_float(((uint32_t)u) << 16);
}

// ---------------- generic zero-fill ----------------
__global__ void k_zero(float* __restrict__ p, int n4) {
    int i = blockIdx.x * blockDim.x + threadIdx.x;
    if (i < n4) ((float4*)p)[i] = make_float4(0.f, 0.f, 0.f, 0.f);
}

// ---------------- h0 = relu(node_feats @ proj_W + proj_b) ----------------
__global__ void k_node_proj(const float* __restrict__ nf, const float* __restrict__ W,
                            const float* __restrict__ b, float* __restrict__ h) {
    int wave = threadIdx.x >> 6, lane = threadIdx.x & 63;
    int v = blockIdx.x * 4 + wave;           // V % 4 == 0
    __shared__ float xs[4][NODE_IN];
    xs[wave][lane] = nf[(size_t)v * NODE_IN + lane];
    if (lane + 64 < NODE_IN) xs[wave][lane + 64] = nf[(size_t)v * NODE_IN + lane + 64];
    __syncthreads();
    float acc = b[lane];
    #pragma unroll
    for (int i = 0; i < NODE_IN; ++i) acc = fmaf(xs[wave][i], W[i * D + lane], acc);
    h[(size_t)v * D + lane] = fmaxf(acc, 0.0f);
}

// ---------------- HedgeP = bf16-permuted relu(edge_feats @ eW1 + eb1) ----------------
// Layout: chunk(b, w, kt) of 512 elems; elem (quad, m, j) = Hedge[e=b*64+w*16+m][k=kt*32+quad*8+j]
__global__ __launch_bounds__(256) void k_edge_hidden(const float* __restrict__ ef,
                              const float* __restrict__ W1,
                              const float* __restrict__ b1, uint16_t* __restrict__ HedgeP) {
    int blk = blockIdx.x;                     // EPAD/8 = 7504 blocks
    int t = threadIdx.x;
    int half = t >> 7, j = t & 127;
    __shared__ float xs[8][EDGE_IN];
    if (t < 8 * EDGE_IN) {
        int el = t / EDGE_IN, c = t % EDGE_IN;
        int e = blk * 8 + el;
        xs[el][c] = (e < E) ? ef[(size_t)e * EDGE_IN + c] : 0.f;
    }
    __syncthreads();
    #pragma unroll
    for (int l = 0; l < 4; ++l) {
        int el = half * 4 + l;
        int e = blk * 8 + el;
        float acc = b1[j];
        #pragma unroll
        for (int i = 0; i < EDGE_IN; ++i) acc = fmaf(xs[el][i], W1[i * EH + j], acc);
        float r = (e < E) ? fmaxf(acc, 0.0f) : 0.0f;
        int bb = e >> 6, ww = (e >> 4) & 3, m = e & 15;
        int kt = j >> 5, quad = (j >> 3) & 3, jj = j & 7;
        size_t off = ((((size_t)(bb * 4 + ww) * 4 + kt) * 4 + quad) * 16 + m) * 8 + jj;
        HedgeP[off] = f2bf(r);
    }
}

// ---------------- W2p: eW2 (128 x 4096 fp32) -> bf16 B-frag-permuted ----------------
// chunk(i, kt, nt) of 512; elem (quad, n0, j) = eW2[k=kt*32+quad*8+j][i*64+nt*16+n0]
__global__ void k_prep_w2(const float* __restrict__ eW2, uint16_t* __restrict__ W2p) {
    int idx = blockIdx.x * 256 + threadIdx.x;           // 524288 total
    int j = idx & 7;
    int n0 = (idx >> 3) & 15;
    int quad = (idx >> 7) & 3;
    int nt = (idx >> 9) & 3;
    int kt = (idx >> 11) & 3;
    int i = idx >> 13;
    int k = kt * 32 + quad * 8 + j;
    int col = i * 64 + nt * 16 + n0;
    W2p[idx] = f2bf(eW2[(size_t)k * 4096 + col]);
}

// ---------------- B2p: eb2 (4096,) viewed [i][o] -> bf16 B-frag-permuted ----------------
// First 4096 elems = real bias fragments; second 4096 = zeros (used by i-half 1 blocks
// so the bias-init MFMA is branch-free).
__global__ void k_prep_b2(const float* __restrict__ eb2, uint16_t* __restrict__ B2p) {
    int idx = blockIdx.x * 256 + threadIdx.x;           // 8192 total
    if (idx >= 4096) { B2p[idx] = 0; return; }
    int j = idx & 7;
    int n0 = (idx >> 3) & 15;
    int quad = (idx >> 7) & 3;
    int nt = (idx >> 9) & 3;
    int kb = (idx >> 11) & 1;
    B2p[idx] = f2bf(eb2[(size_t)(kb * 32 + quad * 8 + j) * 64 + nt * 16 + n0]);
}

// ---------------- Wcp: GRU combined weight (128 x 256) -> bf16 B-frag-permuted ----------------
// Logical Wc: rows k (0..63 = x via Wih, 64..127 = h via Whh); cols c:
//   c in [0,128):  stacked r,z gates  -> gives ir+hr (c<64) and iz+hz (64<=c<128)
//   c in [128,192): inn only (Wih cols 128..191; h rows zero)
//   c in [192,256): hn  only (Whh cols 128..191; x rows zero)
// chunk (ot*4 + kt) of 512; elem (quad, n0, j) = Wc[k=kt*32+quad*8+j][ot*16+n0]
// Also writes bc[256]: combined gate biases matching the column map.
__global__ void k_prep_wc(const float* __restrict__ Wih, const float* __restrict__ Whh,
                          const float* __restrict__ bih, const float* __restrict__ bhh,
                          uint16_t* __restrict__ Wcp, float* __restrict__ bc) {
    int idx = blockIdx.x * 256 + threadIdx.x;           // 32768 total
    int j = idx & 7;
    int n0 = (idx >> 3) & 15;
    int quad = (idx >> 7) & 3;
    int kt = (idx >> 9) & 3;
    int ot = idx >> 11;                                 // 0..15
    int k = kt * 32 + quad * 8 + j;                     // 0..127
    int c = ot * 16 + n0;                               // 0..255
    float val = 0.f;
    if (c < 128) {
        val = (k < 64) ? Wih[(size_t)k * 192 + c] : Whh[(size_t)(k - 64) * 192 + c];
    } else if (c < 192) {
        if (k < 64) val = Wih[(size_t)k * 192 + c];
    } else {
        if (k >= 64) val = Whh[(size_t)(k - 64) * 192 + (c - 64)];
    }
    Wcp[idx] = f2bf(val);
    if (idx < 256) {
        int d = idx & 63;
        float b;
        if (idx < 64)       b = bih[d] + bhh[d];
        else if (idx < 128) b = bih[64 + d] + bhh[64 + d];
        else if (idx < 192) b = bih[128 + d];
        else                b = bhh[128 + d];
        bc[idx] = b;
    }
}

// ---------------- fused We-recompute + message + scatter ----------------
// Grid = 2*NBLK: block bx -> edge-tile b = bx>>1, i-half = bx&1 (i in [32h, 32h+32)).
// Wave w owns output columns [16w, 16w+16). Bias folded via MFMA against B2p.
// Epilogue redesign (r11): h staged TRANSPOSED fp32 (HsT[i][row]) so the per-i h-scale
// reads one ds_read_b128 broadcast per et (4 LDS ops/i/wave vs 16 scalar ds_read_u16 +
// 16 cvts in r10 — the epilogue LDS/VALU pipes were co-limiting with MFMA at 83 us).
__global__ __launch_bounds__(256, 3) void k_message_mfma(
    const uint16_t* __restrict__ HedgeP, const uint16_t* __restrict__ W2p,
    const uint16_t* __restrict__ B2p, const float* __restrict__ h,
    const int* __restrict__ src, const int* __restrict__ dst,
    float* __restrict__ agg) {
    const int bx = blockIdx.x;                // 2*938 blocks
    const int b = bx >> 1;
    const int ibase = (bx & 1) * 32;
    const int t = threadIdx.x;
    const int w = t >> 6, lane = t & 63;      // w = this wave's o-tile (nt)
    const int quad = lane >> 4, n0 = lane & 15;

    __shared__ float HsT[64][68];             // fp32 h TRANSPOSED: [i][edge-row]; 272B stride
    __shared__ int srcv[64], dstv[64];

    if (t < 64) {
        int e = b * 64 + t;
        int sv = 0, dv = -1;
        if (e < E) { sv = src[e]; dv = dst[e]; }
        srcv[t] = sv; dstv[t] = dv;
    }
    __syncthreads();
    // gather h rows (coalesced read), store transposed
    for (int idx = t; idx < 4096; idx += 256) {
        int r = idx >> 6, c = idx & 63;
        HsT[c][r] = h[(size_t)srcv[r] * 64 + c];
    }
    // A-fragments: all 4 edge-tiles x 4 K-tiles (same in every wave; AGPR-resident)
    bf16x8 Af[4][4];
    #pragma unroll
    for (int et = 0; et < 4; ++et)
        #pragma unroll
        for (int kt = 0; kt < 4; ++kt)
            Af[et][kt] = *(const bf16x8*)(HedgeP + (((size_t)(b * 4 + et) * 4 + kt) * 512) + lane * 8);
    __syncthreads();

    // ---- bias init: acc[et] = hA[et] @ b2[:, w-slice]  (zeros for i-half 1) ----
    // hA built from strided HsT scalars + f2bf (once per wave; 4-way bank alias, cheap).
    f32x4 acc[4];
    {
        const uint16_t* b2b = B2p + (size_t)ibase * 128;   // half*4096 elems
        bf16x8 B2f0 = *(const bf16x8*)(b2b + (size_t)(0 * 4 + w) * 512 + lane * 8);
        bf16x8 B2f1 = *(const bf16x8*)(b2b + (size_t)(1 * 4 + w) * 512 + lane * 8);
        #pragma unroll
        for (int et = 0; et < 4; ++et) {
            bf16x8 hA0, hA1;
            #pragma unroll
            for (int j = 0; j < 8; ++j) {
                hA0[j] = (short)f2bf(HsT[quad * 8 + j][et * 16 + n0]);
                hA1[j] = (short)f2bf(HsT[32 + quad * 8 + j][et * 16 + n0]);
            }
            f32x4 z = {};
            z = __builtin_amdgcn_mfma_f32_16x16x32_bf16(hA0, B2f0, z, 0, 0, 0);
            acc[et] = __builtin_amdgcn_mfma_f32_16x16x32_bf16(hA1, B2f1, z, 0, 0, 0);
        }
    }

    // ---- main loop over this block's 32 i; 4 B-frag loads + 4 b128 h-broadcasts per i ----
    for (int ii = 0; ii < 32; ++ii) {
        const int i = ibase + ii;
        const uint16_t* wb = W2p + (size_t)i * 8192 + lane * 8;
        bf16x8 Bf0 = *(const bf16x8*)(wb + (size_t)(0 * 4 + w) * 512);
        bf16x8 Bf1 = *(const bf16x8*)(wb + (size_t)(1 * 4 + w) * 512);
        bf16x8 Bf2 = *(const bf16x8*)(wb + (size_t)(2 * 4 + w) * 512);
        bf16x8 Bf3 = *(const bf16x8*)(wb + (size_t)(3 * 4 + w) * 512);
        #pragma unroll
        for (int et = 0; et < 4; ++et) {
            f32x4 tmp = {};
            tmp = __builtin_amdgcn_mfma_f32_16x16x32_bf16(Af[et][0], Bf0, tmp, 0, 0, 0);
            tmp = __builtin_amdgcn_mfma_f32_16x16x32_bf16(Af[et][1], Bf1, tmp, 0, 0, 0);
            tmp = __builtin_amdgcn_mfma_f32_16x16x32_bf16(Af[et][2], Bf2, tmp, 0, 0, 0);
            tmp = __builtin_amdgcn_mfma_f32_16x16x32_bf16(Af[et][3], Bf3, tmp, 0, 0, 0);
            // 16B-aligned broadcast read: rows r0..r0+3 of h-column i (quad-uniform addr)
            f32x4 hv = *(const f32x4*)(&HsT[i][et * 16 + quad * 4]);
            acc[et][0] = fmaf(hv[0], tmp[0], acc[et][0]);
            acc[et][1] = fmaf(hv[1], tmp[1], acc[et][1]);
            acc[et][2] = fmaf(hv[2], tmp[2], acc[et][2]);
            acc[et][3] = fmaf(hv[3], tmp[3], acc[et][3]);
        }
    }

    // ---- scatter: each wave owns columns w*16..w*16+15 ----
    #pragma unroll
    for (int et = 0; et < 4; ++et) {
        #pragma unroll
        for (int reg = 0; reg < 4; ++reg) {
            int d = dstv[et * 16 + quad * 4 + reg];
            if (d >= 0)
                atomicAdd(agg + (size_t)d * 64 + w * 16 + n0, acc[et][reg]);
        }
    }
}

// ---------------- MFMA GRU: gates = [relu(agg+b)|h] @ Wc; h update; zeroes agg ----------------
// Block = 32 nodes, 4 waves; wave w owns gate columns [64w, 64w+64) (4 o-tiles).
// Gate pre-acts round-trip LDS as bf16; h update reads fp32 hcur (recurrence stays fp32).
__global__ __launch_bounds__(256) void k_gru_mfma(
    float* __restrict__ agg, const float* __restrict__ convb,
    const uint16_t* __restrict__ Wcp, const float* __restrict__ bc,
    float* __restrict__ hcur) {
    const int blk = blockIdx.x;               // GRUBLK = 938
    const int v0 = blk * 32;
    const int t = threadIdx.x;
    const int w = t >> 6, lane = t & 63;
    const int quad = lane >> 4, n0 = lane & 15;

    __shared__ uint16_t As[32][136];          // [x|h] bf16, 272B row stride (16B-aligned frags)
    __shared__ uint16_t Gs[32][264];          // gate pre-acts bf16, 528B stride

    // stage A and zero agg
    for (int idx = t; idx < 2048; idx += 256) {
        int r = idx >> 6, c = idx & 63;
        int v = v0 + r;
        if (v < V) {
            size_t off = (size_t)v * 64 + c;
            float x = fmaxf(agg[off] + convb[c], 0.f);
            agg[off] = 0.f;                   // pre-zero for next step's atomics
            As[r][c] = f2bf(x);
            As[r][64 + c] = f2bf(hcur[off]);
        } else {
            As[r][c] = 0; As[r][64 + c] = 0;
        }
    }
    __syncthreads();

    // A-fragments: 2 row-tiles x 4 K-tiles
    bf16x8 Af[2][4];
    #pragma unroll
    for (int et = 0; et < 2; ++et)
        #pragma unroll
        for (int kt = 0; kt < 4; ++kt)
            Af[et][kt] = *(const bf16x8*)(&As[et * 16 + n0][kt * 32 + quad * 8]);

    // MFMA: wave w's 4 o-tiles (cols 64w..64w+63 of 256)
    f32x4 acc[2][4] = {};
    #pragma unroll
    for (int ot4 = 0; ot4 < 4; ++ot4) {
        const uint16_t* wb = Wcp + (size_t)((w * 4 + ot4) * 4) * 512 + lane * 8;
        bf16x8 B0 = *(const bf16x8*)(wb + 0 * 512);
        bf16x8 B1 = *(const bf16x8*)(wb + 1 * 512);
        bf16x8 B2 = *(const bf16x8*)(wb + 2 * 512);
        bf16x8 B3 = *(const bf16x8*)(wb + 3 * 512);
        #pragma unroll
        for (int et = 0; et < 2; ++et) {
            f32x4 a = acc[et][ot4];
            a = __builtin_amdgcn_mfma_f32_16x16x32_bf16(Af[et][0], B0, a, 0, 0, 0);
            a = __builtin_amdgcn_mfma_f32_16x16x32_bf16(Af[et][1], B1, a, 0, 0, 0);
            a = __builtin_amdgcn_mfma_f32_16x16x32_bf16(Af[et][2], B2, a, 0, 0, 0);
            a = __builtin_amdgcn_mfma_f32_16x16x32_bf16(Af[et][3], B3, a, 0, 0, 0);
            acc[et][ot4] = a;
        }
    }
    // export gates to LDS (C-layout: col=n0, row=quad*4+reg)
    #pragma unroll
    for (int et = 0; et < 2; ++et)
        #pragma unroll
        for (int ot4 = 0; ot4 < 4; ++ot4)
            #pragma unroll
            for (int reg = 0; reg < 4; ++reg)
                Gs[et * 16 + quad * 4 + reg][(w * 4 + ot4) * 16 + n0] = f2bf(acc[et][ot4][reg]);
    __syncthreads();

    // epilogue: per (node, d)
    for (int idx = t; idx < 2048; idx += 256) {
        int r = idx >> 6, d = idx & 63;
        int v = v0 + r;
        if (v >= V) continue;
        size_t off = (size_t)v * 64 + d;
        float rp   = bf2f(Gs[r][d])        + bc[d];
        float zp   = bf2f(Gs[r][64 + d])   + bc[64 + d];
        float innv = bf2f(Gs[r][128 + d])  + bc[128 + d];
        float hnv  = bf2f(Gs[r][192 + d])  + bc[192 + d];
        float hv = hcur[off];
        float rr = sigmoidf_(rp);
        float zz = sigmoidf_(zp);
        float nn = tanhf_(innv + rr * hnv);
        hcur[off] = (1.f - zz) * nn + zz * hv;
    }
}

// ---------------- segment start offsets from sorted gids ----------------
__global__ void k_seg(const int* __restrict__ gids, int* __restrict__ start) {
    int v = blockIdx.x * blockDim.x + threadIdx.x;
    if (v > V) return;
    int cur = (v < V) ? gids[v] : G;
    int prev = (v == 0) ? -1 : gids[v - 1];
    for (int g = prev + 1; g <= cur; ++g) start[g] = v;
}

// ---------------- Set2Set 3-layer LSTM step: q_star -> q ----------------
#define LS_GPB 8
__global__ __launch_bounds__(256) void k_lstm(const float* __restrict__ q_star,
    const float* __restrict__ Wih0, const float* __restrict__ bih0,
    const float* __restrict__ Whh0, const float* __restrict__ bhh0,
    const float* __restrict__ Wih1, const float* __restrict__ bih1,
    const float* __restrict__ Whh1, const float* __restrict__ bhh1,
    const float* __restrict__ Wih2, const float* __restrict__ bih2,
    const float* __restrict__ Whh2, const float* __restrict__ bhh2,
    float* __restrict__ hs, float* __restrict__ cs, float* __restrict__ q) {
    int g0 = blockIdx.x * LS_GPB;             // G % 8 == 0
    int j = threadIdx.x;                       // 0..255
    __shared__ float xs[LS_GPB][128];
    __shared__ float hl[LS_GPB][64];
    __shared__ float gates[LS_GPB][256];
    for (int idx = j; idx < LS_GPB * 128; idx += 256) {
        int n = idx >> 7, d = idx & 127;
        xs[n][d] = q_star[(size_t)(g0 + n) * 128 + d];
    }
    const float* Wihs[3] = {Wih0, Wih1, Wih2};
    const float* bihs[3] = {bih0, bih1, bih2};
    const float* Whhs[3] = {Whh0, Whh1, Whh2};
    const float* bhhs[3] = {bhh0, bhh1, bhh2};
    const int dins[3] = {128, 64, 64};
    for (int l = 0; l < 3; ++l) {
        for (int idx = j; idx < LS_GPB * 64; idx += 256) {
            int n = idx >> 6, d = idx & 63;
            hl[n][d] = hs[(size_t)l * G * 64 + (size_t)(g0 + n) * 64 + d];
        }
        __syncthreads();
        float acc[LS_GPB];
        float bsum = bihs[l][j] + bhhs[l][j];
        #pragma unroll
        for (int n = 0; n < LS_GPB; ++n) acc[n] = bsum;
        const float* Wih = Wihs[l];
        int din = dins[l];
        for (int i = 0; i < din; ++i) {
            float w = Wih[i * 256 + j];
            #pragma unroll
            for (int n = 0; n < LS_GPB; ++n) acc[n] = fmaf(xs[n][i], w, acc[n]);
        }
        const float* Whh = Whhs[l];
        for (int i = 0; i < 64; ++i) {
            float w = Whh[i * 256 + j];
            #pragma unroll
            for (int n = 0; n < LS_GPB; ++n) acc[n] = fmaf(hl[n][i], w, acc[n]);
        }
        #pragma unroll
        for (int n = 0; n < LS_GPB; ++n) gates[n][j] = acc[n];
        __syncthreads();
        for (int idx = j; idx < LS_GPB * 64; idx += 256) {
            int n = idx >> 6, d = idx & 63;
            float ig = gates[n][d], fg = gates[n][64 + d];
            float gt = gates[n][128 + d], og = gates[n][192 + d];
            size_t off = (size_t)l * G * 64 + (size_t)(g0 + n) * 64 + d;
            float c = sigmoidf_(fg) * cs[off] + sigmoidf_(ig) * tanhf_(gt);
            float hnew = sigmoidf_(og) * tanhf_(c);
            cs[off] = c;
            hs[off] = hnew;
            xs[n][d] = hnew;
            if (l == 2) q[(size_t)(g0 + n) * 64 + d] = hnew;
        }
        __syncthreads();
    }
}

// ---------------- attention softmax + readout -> q_star ----------------
__global__ void k_attention(const float* __restrict__ h, const float* __restrict__ q,
                            const int* __restrict__ segs, float* __restrict__ q_star) {
    int g = blockIdx.x;
    int lane = threadIdx.x;                   // 64 threads = 1 wave
    int vs = segs[g], ve = segs[g + 1];
    float qv = q[(size_t)g * 64 + lane];
    float m = -INFINITY;
    for (int v = vs; v < ve; ++v) {
        float p = h[(size_t)v * 64 + lane] * qv;
        #pragma unroll
        for (int off = 32; off > 0; off >>= 1) p += __shfl_xor(p, off, 64);
        m = fmaxf(m, p);
    }
    float s = 0.f, acc = 0.f;
    for (int v = vs; v < ve; ++v) {
        float hv = h[(size_t)v * 64 + lane];
        float p = hv * qv;
        #pragma unroll
        for (int off = 32; off > 0; off >>= 1) p += __shfl_xor(p, off, 64);
        float ex = __expf(p - m);
        s += ex;
        acc = fmaf(hv, ex, acc);
    }
    float r = (ve > vs) ? acc / s : 0.f;
    q_star[(size_t)g * 128 + lane] = qv;
    q_star[(size_t)g * 128 + 64 + lane] = r;
}

// ---------------- final MLPs ----------------
__global__ void k_final(const float* __restrict__ q_star,
                        const float* __restrict__ pW, const float* __restrict__ pb,
                        const float* __restrict__ qW1, const float* __restrict__ qb1,
                        const float* __restrict__ qW2, const float* __restrict__ qb2,
                        const float* __restrict__ qW3, const float* __restrict__ qb3,
                        float* __restrict__ out) {
    int g = blockIdx.x;
    int lane = threadIdx.x;                   // 64 threads
    __shared__ float buf[128];
    buf[lane] = q_star[(size_t)g * 128 + lane];
    buf[64 + lane] = q_star[(size_t)g * 128 + 64 + lane];
    __syncthreads();
    float y = pb[lane];
    #pragma unroll 8
    for (int i = 0; i < 128; ++i) y = fmaf(buf[i], pW[i * 64 + lane], y);
    y = fmaxf(y, 0.f);
    __syncthreads(); buf[lane] = y; __syncthreads();
    float y1 = qb1[lane];
    #pragma unroll 8
    for (int i = 0; i < 64; ++i) y1 = fmaf(buf[i], qW1[i * 64 + lane], y1);
    y1 = fmaxf(y1, 0.f);
    __syncthreads(); buf[lane] = y1; __syncthreads();
    float y2 = qb2[lane];
    #pragma unroll 8
    for (int i = 0; i < 64; ++i) y2 = fmaf(buf[i], qW2[i * 64 + lane], y2);
    y2 = fmaxf(y2, 0.f);
    float p = y2 * qW3[lane];
    #pragma unroll
    for (int off = 32; off > 0; off >>= 1) p += __shfl_xor(p, off, 64);
    if (lane == 0) out[g] = p + qb3[0];
}

extern "C" void kernel_launch(void* const* d_in, const int* in_sizes, int n_in,
                              void* d_out, int out_size, void* d_ws, size_t ws_size,
                              hipStream_t stream) {
    const float* node_feats = (const float*)d_in[0];
    const float* edge_feats = (const float*)d_in[1];
    const int*   src        = (const int*)d_in[2];
    const int*   dst        = (const int*)d_in[3];
    const int*   gids       = (const int*)d_in[4];
    const float* proj_W     = (const float*)d_in[5];
    const float* proj_b     = (const float*)d_in[6];
    const float* eW1        = (const float*)d_in[7];
    const float* eb1        = (const float*)d_in[8];
    const float* eW2        = (const float*)d_in[9];
    const float* eb2        = (const float*)d_in[10];
    const float* conv_b     = (const float*)d_in[11];
    const float* gru_Wih    = (const float*)d_in[12];
    const float* gru_bih    = (const float*)d_in[13];
    const float* gru_Whh    = (const float*)d_in[14];
    const float* gru_bhh    = (const float*)d_in[15];
    const float* pW         = (const float*)d_in[16];
    const float* pb         = (const float*)d_in[17];
    const float* qW1        = (const float*)d_in[18];
    const float* qb1        = (const float*)d_in[19];
    const float* qW2        = (const float*)d_in[20];
    const float* qb2        = (const float*)d_in[21];
    const float* qW3        = (const float*)d_in[22];
    const float* qb3        = (const float*)d_in[23];
    const float* lWih0 = (const float*)d_in[24]; const float* lbih0 = (const float*)d_in[25];
    const float* lWhh0 = (const float*)d_in[26]; const float* lbhh0 = (const float*)d_in[27];
    const float* lWih1 = (const float*)d_in[28]; const float* lbih1 = (const float*)d_in[29];
    const float* lWhh1 = (const float*)d_in[30]; const float* lbhh1 = (const float*)d_in[31];
    const float* lWih2 = (const float*)d_in[32]; const float* lbih2 = (const float*)d_in[33];
    const float* lWhh2 = (const float*)d_in[34]; const float* lbhh2 = (const float*)d_in[35];

    // ---- workspace layout: EXACT round-7 footprint (34,562,756 B, proven to fit).
    // Wcp/bc TIME-ALIASED over hsbuf (live only during MP phase; hs/cs zeroed after MP).
    char* ws = (char*)d_ws;
    uint16_t* HedgeP = (uint16_t*)(ws + 0);                      // 15,368,192 B (EPAD rows)
    uint16_t* W2p    = (uint16_t*)(ws + 15368192);               //  1,048,576 B
    uint16_t* B2p    = (uint16_t*)(ws + 16416768);               //     16,384 B (real + zero half)
    float*    hcur   = (float*)(ws + 16433152);                  //  7,680,000 B
    float*    agg    = (float*)(ws + 24113152);                  //  7,680,000 B
    float*    q_star = (float*)(ws + 31793152);                  //    614,400 B
    float*    hsbuf  = (float*)(ws + 32407552);                  //    921,600 B
    float*    csbuf  = (float*)(ws + 33329152);                  //    921,600 B
    float*    qbuf   = (float*)(ws + 34250752);                  //    307,200 B
    int*      segs   = (int*)(ws + 34557952);                    //      4,804 B
    uint16_t* Wcp    = (uint16_t*)hsbuf;                         // 65,536 B alias (MP phase only)
    float*    bc     = (float*)(ws + 32407552 + 65536);          //    1,024 B alias

    // --- one-time phase ---
    k_node_proj<<<V / 4, 256, 0, stream>>>(node_feats, proj_W, proj_b, hcur);
    k_edge_hidden<<<EPAD / 8, 256, 0, stream>>>(edge_feats, eW1, eb1, HedgeP);
    k_prep_w2<<<2048, 256, 0, stream>>>(eW2, W2p);
    k_prep_b2<<<32, 256, 0, stream>>>(eb2, B2p);
    k_prep_wc<<<128, 256, 0, stream>>>(gru_Wih, gru_Whh, gru_bih, gru_bhh, Wcp, bc);
    k_seg<<<(V + 1 + 255) / 256, 256, 0, stream>>>(gids, segs);
    // zero agg once (k_gru_mfma re-zeroes it each step after consuming)
    k_zero<<<(480000 + 255) / 256, 256, 0, stream>>>(agg, 480000);  // V*64/4

    // --- message passing (uses Wcp/bc aliased over hsbuf) ---
    for (int t = 0; t < N_MP; ++t) {
        k_message_mfma<<<NBLK * 2, 256, 0, stream>>>(HedgeP, W2p, B2p, hcur, src, dst, agg);
        k_gru_mfma<<<GRUBLK, 256, 0, stream>>>(agg, conv_b, Wcp, bc, hcur);
    }

    // zero q_star + hs + cs AFTER MP (wipes the Wcp alias; 2,457,600 B = 153,600 float4)
    k_zero<<<(153600 + 255) / 256, 256, 0, stream>>>(q_star, 153600);

    // --- Set2Set ---
    for (int s = 0; s < N_S2S; ++s) {
        k_lstm<<<G / LS_GPB, 256, 0, stream>>>(q_star,
            lWih0, lbih0, lWhh0, lbhh0,
            lWih1, lbih1, lWhh1, lbhh1,
            lWih2, lbih2, lWhh2, lbhh2,
            hsbuf, csbuf, qbuf);
        k_attention<<<G, 64, 0, stream>>>(hcur, qbuf, segs, q_star);
    }

    // --- predict MLPs ---
    k_final<<<G, 64, 0, stream>>>(q_star, pW, pb, qW1, qb1, qW2, qb2, qW3, qb3,
                                  (float*)d_out);
}

// Round 12
// 953.986 us; speedup vs baseline: 16.0670x; 16.0670x over previous
//
#include <hip/hip_runtime.h>
#include <stdint.h>
#include <math.h>

#define V 30000
#define E 60000
#define G 1200
#define D 64
#define NODE_IN 74
#define EDGE_IN 12
#define EH 128
#define N_MP 6
#define N_S2S 6

#define NBLK ((E + 63) / 64)   // 938 edge-tiles of 64
#define EPAD (NBLK * 64)       // 60032 padded edge rows
#define GRUBLK ((V + 31) / 32) // 938 node-tiles of 32

typedef short bf16x8 __attribute__((ext_vector_type(8)));
typedef float f32x4 __attribute__((ext_vector_type(4)));

__device__ __forceinline__ float sigmoidf_(float x) {
    return 1.0f / (1.0f + __expf(-x));
}
__device__ __forceinline__ float tanhf_(float x) {
    float t = __expf(-2.0f * fabsf(x));
    float r = (1.0f - t) / (1.0f + t);
    return copysignf(r, x);
}
__device__ __forceinline__ uint16_t f2bf(float f) {
    uint32_t u = __float_as_uint(f);
    u += 0x7fffu + ((u >> 16) & 1u);
    return (uint16_t)(u >> 16);
}
__device__ __forceinline__ float bf2f(uint16_t u) {
    return __uint_as_float(((uint32_t)u) << 16);
}

// ---------------- generic zero-fill ----------------
__global__ void k_zero(float* __restrict__ p, int n4) {
    int i = blockIdx.x * blockDim.x + threadIdx.x;
    if (i < n4) ((float4*)p)[i] = make_float4(0.f, 0.f, 0.f, 0.f);
}

// ---------------- h0 = relu(node_feats @ proj_W + proj_b) ----------------
__global__ void k_node_proj(const float* __restrict__ nf, const float* __restrict__ W,
                            const float* __restrict__ b, float* __restrict__ h) {
    int wave = threadIdx.x >> 6, lane = threadIdx.x & 63;
    int v = blockIdx.x * 4 + wave;           // V % 4 == 0
    __shared__ float xs[4][NODE_IN];
    xs[wave][lane] = nf[(size_t)v * NODE_IN + lane];
    if (lane + 64 < NODE_IN) xs[wave][lane + 64] = nf[(size_t)v * NODE_IN + lane + 64];
    __syncthreads();
    float acc = b[lane];
    #pragma unroll
    for (int i = 0; i < NODE_IN; ++i) acc = fmaf(xs[wave][i], W[i * D + lane], acc);
    h[(size_t)v * D + lane] = fmaxf(acc, 0.0f);
}

// ---------------- HedgeP = bf16-permuted relu(edge_feats @ eW1 + eb1) ----------------
// Layout: chunk(b, w, kt) of 512 elems; elem (quad, m, j) = Hedge[e=b*64+w*16+m][k=kt*32+quad*8+j]
__global__ __launch_bounds__(256) void k_edge_hidden(const float* __restrict__ ef,
                              const float* __restrict__ W1,
                              const float* __restrict__ b1, uint16_t* __restrict__ HedgeP) {
    int blk = blockIdx.x;                     // EPAD/8 = 7504 blocks
    int t = threadIdx.x;
    int half = t >> 7, j = t & 127;
    __shared__ float xs[8][EDGE_IN];
    if (t < 8 * EDGE_IN) {
        int el = t / EDGE_IN, c = t % EDGE_IN;
        int e = blk * 8 + el;
        xs[el][c] = (e < E) ? ef[(size_t)e * EDGE_IN + c] : 0.f;
    }
    __syncthreads();
    #pragma unroll
    for (int l = 0; l < 4; ++l) {
        int el = half * 4 + l;
        int e = blk * 8 + el;
        float acc = b1[j];
        #pragma unroll
        for (int i = 0; i < EDGE_IN; ++i) acc = fmaf(xs[el][i], W1[i * EH + j], acc);
        float r = (e < E) ? fmaxf(acc, 0.0f) : 0.0f;
        int bb = e >> 6, ww = (e >> 4) & 3, m = e & 15;
        int kt = j >> 5, quad = (j >> 3) & 3, jj = j & 7;
        size_t off = ((((size_t)(bb * 4 + ww) * 4 + kt) * 4 + quad) * 16 + m) * 8 + jj;
        HedgeP[off] = f2bf(r);
    }
}

// ---------------- W2p: eW2 (128 x 4096 fp32) -> bf16 B-frag-permuted ----------------
// chunk(i, kt, nt) of 512; elem (quad, n0, j) = eW2[k=kt*32+quad*8+j][i*64+nt*16+n0]
__global__ void k_prep_w2(const float* __restrict__ eW2, uint16_t* __restrict__ W2p) {
    int idx = blockIdx.x * 256 + threadIdx.x;           // 524288 total
    int j = idx & 7;
    int n0 = (idx >> 3) & 15;
    int quad = (idx >> 7) & 3;
    int nt = (idx >> 9) & 3;
    int kt = (idx >> 11) & 3;
    int i = idx >> 13;
    int k = kt * 32 + quad * 8 + j;
    int col = i * 64 + nt * 16 + n0;
    W2p[idx] = f2bf(eW2[(size_t)k * 4096 + col]);
}

// ---------------- B2p: eb2 (4096,) viewed [i][o] -> bf16 B-frag-permuted ----------------
// First 4096 elems = real bias fragments; second 4096 = zeros (used by i-half 1 blocks
// so the bias-init MFMA is branch-free).
__global__ void k_prep_b2(const float* __restrict__ eb2, uint16_t* __restrict__ B2p) {
    int idx = blockIdx.x * 256 + threadIdx.x;           // 8192 total
    if (idx >= 4096) { B2p[idx] = 0; return; }
    int j = idx & 7;
    int n0 = (idx >> 3) & 15;
    int quad = (idx >> 7) & 3;
    int nt = (idx >> 9) & 3;
    int kb = (idx >> 11) & 1;
    B2p[idx] = f2bf(eb2[(size_t)(kb * 32 + quad * 8 + j) * 64 + nt * 16 + n0]);
}

// ---------------- Wcp: GRU combined weight (128 x 256) -> bf16 B-frag-permuted ----------------
// Logical Wc: rows k (0..63 = x via Wih, 64..127 = h via Whh); cols c:
//   c in [0,128):  stacked r,z gates  -> gives ir+hr (c<64) and iz+hz (64<=c<128)
//   c in [128,192): inn only (Wih cols 128..191; h rows zero)
//   c in [192,256): hn  only (Whh cols 128..191; x rows zero)
// chunk (ot*4 + kt) of 512; elem (quad, n0, j) = Wc[k=kt*32+quad*8+j][ot*16+n0]
// Also writes bc[256]: combined gate biases matching the column map.
__global__ void k_prep_wc(const float* __restrict__ Wih, const float* __restrict__ Whh,
                          const float* __restrict__ bih, const float* __restrict__ bhh,
                          uint16_t* __restrict__ Wcp, float* __restrict__ bc) {
    int idx = blockIdx.x * 256 + threadIdx.x;           // 32768 total
    int j = idx & 7;
    int n0 = (idx >> 3) & 15;
    int quad = (idx >> 7) & 3;
    int kt = (idx >> 9) & 3;
    int ot = idx >> 11;                                 // 0..15
    int k = kt * 32 + quad * 8 + j;                     // 0..127
    int c = ot * 16 + n0;                               // 0..255
    float val = 0.f;
    if (c < 128) {
        val = (k < 64) ? Wih[(size_t)k * 192 + c] : Whh[(size_t)(k - 64) * 192 + c];
    } else if (c < 192) {
        if (k < 64) val = Wih[(size_t)k * 192 + c];
    } else {
        if (k >= 64) val = Whh[(size_t)(k - 64) * 192 + (c - 64)];
    }
    Wcp[idx] = f2bf(val);
    if (idx < 256) {
        int d = idx & 63;
        float b;
        if (idx < 64)       b = bih[d] + bhh[d];
        else if (idx < 128) b = bih[64 + d] + bhh[64 + d];
        else if (idx < 192) b = bih[128 + d];
        else                b = bhh[128 + d];
        bc[idx] = b;
    }
}

// ---------------- fused We-recompute + message + scatter (EXACT r9 text — PARKED) ----------------
// Grid = 2*NBLK: block bx -> edge-tile b = bx>>1, i-half = bx&1 (i in [32h, 32h+32)).
// Wave w owns output columns [16w, 16w+16). Bias via MFMA against B2p (zeros for half 1).
// DO NOT TOUCH: codegen is bistable. This shape = VGPR 60, Af AGPR-resident, 81 us.
// r10 (LDS anti-remat alias) = neutral; r11 (fp32 HsT epilogue) = scratch-spill blowup.
__global__ __launch_bounds__(256, 3) void k_message_mfma(
    const uint16_t* __restrict__ HedgeP, const uint16_t* __restrict__ W2p,
    const uint16_t* __restrict__ B2p, const float* __restrict__ h,
    const int* __restrict__ src, const int* __restrict__ dst,
    float* __restrict__ agg) {
    const int bx = blockIdx.x;                // 2*938 blocks
    const int b = bx >> 1;
    const int ibase = (bx & 1) * 32;
    const int t = threadIdx.x;
    const int w = t >> 6, lane = t & 63;      // w = this wave's o-tile (nt)
    const int quad = lane >> 4, n0 = lane & 15;

    __shared__ uint16_t HsU[64][72];          // bf16 h rows; 144B stride keeps frags 16B-aligned
    __shared__ int srcv[64], dstv[64];

    if (t < 64) {
        int e = b * 64 + t;
        int sv = 0, dv = -1;
        if (e < E) { sv = src[e]; dv = dst[e]; }
        srcv[t] = sv; dstv[t] = dv;
    }
    __syncthreads();
    for (int idx = t; idx < 4096; idx += 256) {
        int r = idx >> 6, c = idx & 63;
        HsU[r][c] = f2bf(h[(size_t)srcv[r] * 64 + c]);
    }
    // A-fragments: all 4 edge-tiles x 4 K-tiles (same in every wave)
    bf16x8 Af[4][4];
    #pragma unroll
    for (int et = 0; et < 4; ++et)
        #pragma unroll
        for (int kt = 0; kt < 4; ++kt)
            Af[et][kt] = *(const bf16x8*)(HedgeP + (((size_t)(b * 4 + et) * 4 + kt) * 512) + lane * 8);
    __syncthreads();

    // ---- bias init: acc[et] = hA[et] @ b2[:, w-slice]  (zeros for i-half 1) ----
    f32x4 acc[4];
    {
        const uint16_t* b2b = B2p + (size_t)ibase * 128;   // half*4096 elems
        bf16x8 B2f0 = *(const bf16x8*)(b2b + (size_t)(0 * 4 + w) * 512 + lane * 8);
        bf16x8 B2f1 = *(const bf16x8*)(b2b + (size_t)(1 * 4 + w) * 512 + lane * 8);
        #pragma unroll
        for (int et = 0; et < 4; ++et) {
            bf16x8 hA0 = *(const bf16x8*)(&HsU[et * 16 + n0][quad * 8]);
            bf16x8 hA1 = *(const bf16x8*)(&HsU[et * 16 + n0][32 + quad * 8]);
            f32x4 z = {};
            z = __builtin_amdgcn_mfma_f32_16x16x32_bf16(hA0, B2f0, z, 0, 0, 0);
            acc[et] = __builtin_amdgcn_mfma_f32_16x16x32_bf16(hA1, B2f1, z, 0, 0, 0);
        }
    }

    // ---- main loop over this block's 32 i; 4 B-frag loads (own o-slice) per i ----
    for (int ii = 0; ii < 32; ++ii) {
        const int i = ibase + ii;
        const uint16_t* wb = W2p + (size_t)i * 8192 + lane * 8;
        bf16x8 Bf0 = *(const bf16x8*)(wb + (size_t)(0 * 4 + w) * 512);
        bf16x8 Bf1 = *(const bf16x8*)(wb + (size_t)(1 * 4 + w) * 512);
        bf16x8 Bf2 = *(const bf16x8*)(wb + (size_t)(2 * 4 + w) * 512);
        bf16x8 Bf3 = *(const bf16x8*)(wb + (size_t)(3 * 4 + w) * 512);
        #pragma unroll
        for (int et = 0; et < 4; ++et) {
            f32x4 tmp = {};
            tmp = __builtin_amdgcn_mfma_f32_16x16x32_bf16(Af[et][0], Bf0, tmp, 0, 0, 0);
            tmp = __builtin_amdgcn_mfma_f32_16x16x32_bf16(Af[et][1], Bf1, tmp, 0, 0, 0);
            tmp = __builtin_amdgcn_mfma_f32_16x16x32_bf16(Af[et][2], Bf2, tmp, 0, 0, 0);
            tmp = __builtin_amdgcn_mfma_f32_16x16x32_bf16(Af[et][3], Bf3, tmp, 0, 0, 0);
            int r0 = et * 16 + quad * 4;
            acc[et][0] = fmaf(bf2f(HsU[r0 + 0][i]), tmp[0], acc[et][0]);
            acc[et][1] = fmaf(bf2f(HsU[r0 + 1][i]), tmp[1], acc[et][1]);
            acc[et][2] = fmaf(bf2f(HsU[r0 + 2][i]), tmp[2], acc[et][2]);
            acc[et][3] = fmaf(bf2f(HsU[r0 + 3][i]), tmp[3], acc[et][3]);
        }
    }

    // ---- scatter: each wave owns columns w*16..w*16+15 ----
    #pragma unroll
    for (int et = 0; et < 4; ++et) {
        #pragma unroll
        for (int reg = 0; reg < 4; ++reg) {
            int d = dstv[et * 16 + quad * 4 + reg];
            if (d >= 0)
                atomicAdd(agg + (size_t)d * 64 + w * 16 + n0, acc[et][reg]);
        }
    }
}

// ---------------- MFMA GRU: gates = [relu(agg+b)|h] @ Wc; h update; zeroes agg ----------------
// Block = 32 nodes, 4 waves; wave w owns gate columns [64w, 64w+64) (4 o-tiles).
// Gate pre-acts round-trip LDS as bf16; h update reads fp32 hcur (recurrence stays fp32).
__global__ __launch_bounds__(256) void k_gru_mfma(
    float* __restrict__ agg, const float* __restrict__ convb,
    const uint16_t* __restrict__ Wcp, const float* __restrict__ bc,
    float* __restrict__ hcur) {
    const int blk = blockIdx.x;               // GRUBLK = 938
    const int v0 = blk * 32;
    const int t = threadIdx.x;
    const int w = t >> 6, lane = t & 63;
    const int quad = lane >> 4, n0 = lane & 15;

    __shared__ uint16_t As[32][136];          // [x|h] bf16, 272B row stride (16B-aligned frags)
    __shared__ uint16_t Gs[32][264];          // gate pre-acts bf16, 528B stride

    // stage A and zero agg
    for (int idx = t; idx < 2048; idx += 256) {
        int r = idx >> 6, c = idx & 63;
        int v = v0 + r;
        if (v < V) {
            size_t off = (size_t)v * 64 + c;
            float x = fmaxf(agg[off] + convb[c], 0.f);
            agg[off] = 0.f;                   // pre-zero for next step's atomics
            As[r][c] = f2bf(x);
            As[r][64 + c] = f2bf(hcur[off]);
        } else {
            As[r][c] = 0; As[r][64 + c] = 0;
        }
    }
    __syncthreads();

    // A-fragments: 2 row-tiles x 4 K-tiles
    bf16x8 Af[2][4];
    #pragma unroll
    for (int et = 0; et < 2; ++et)
        #pragma unroll
        for (int kt = 0; kt < 4; ++kt)
            Af[et][kt] = *(const bf16x8*)(&As[et * 16 + n0][kt * 32 + quad * 8]);

    // MFMA: wave w's 4 o-tiles (cols 64w..64w+63 of 256)
    f32x4 acc[2][4] = {};
    #pragma unroll
    for (int ot4 = 0; ot4 < 4; ++ot4) {
        const uint16_t* wb = Wcp + (size_t)((w * 4 + ot4) * 4) * 512 + lane * 8;
        bf16x8 B0 = *(const bf16x8*)(wb + 0 * 512);
        bf16x8 B1 = *(const bf16x8*)(wb + 1 * 512);
        bf16x8 B2 = *(const bf16x8*)(wb + 2 * 512);
        bf16x8 B3 = *(const bf16x8*)(wb + 3 * 512);
        #pragma unroll
        for (int et = 0; et < 2; ++et) {
            f32x4 a = acc[et][ot4];
            a = __builtin_amdgcn_mfma_f32_16x16x32_bf16(Af[et][0], B0, a, 0, 0, 0);
            a = __builtin_amdgcn_mfma_f32_16x16x32_bf16(Af[et][1], B1, a, 0, 0, 0);
            a = __builtin_amdgcn_mfma_f32_16x16x32_bf16(Af[et][2], B2, a, 0, 0, 0);
            a = __builtin_amdgcn_mfma_f32_16x16x32_bf16(Af[et][3], B3, a, 0, 0, 0);
            acc[et][ot4] = a;
        }
    }
    // export gates to LDS (C-layout: col=n0, row=quad*4+reg)
    #pragma unroll
    for (int et = 0; et < 2; ++et)
        #pragma unroll
        for (int ot4 = 0; ot4 < 4; ++ot4)
            #pragma unroll
            for (int reg = 0; reg < 4; ++reg)
                Gs[et * 16 + quad * 4 + reg][(w * 4 + ot4) * 16 + n0] = f2bf(acc[et][ot4][reg]);
    __syncthreads();

    // epilogue: per (node, d)
    for (int idx = t; idx < 2048; idx += 256) {
        int r = idx >> 6, d = idx & 63;
        int v = v0 + r;
        if (v >= V) continue;
        size_t off = (size_t)v * 64 + d;
        float rp   = bf2f(Gs[r][d])        + bc[d];
        float zp   = bf2f(Gs[r][64 + d])   + bc[64 + d];
        float innv = bf2f(Gs[r][128 + d])  + bc[128 + d];
        float hnv  = bf2f(Gs[r][192 + d])  + bc[192 + d];
        float hv = hcur[off];
        float rr = sigmoidf_(rp);
        float zz = sigmoidf_(zp);
        float nn = tanhf_(innv + rr * hnv);
        hcur[off] = (1.f - zz) * nn + zz * hv;
    }
}

// ---------------- segment start offsets from sorted gids ----------------
__global__ void k_seg(const int* __restrict__ gids, int* __restrict__ start) {
    int v = blockIdx.x * blockDim.x + threadIdx.x;
    if (v > V) return;
    int cur = (v < V) ? gids[v] : G;
    int prev = (v == 0) ? -1 : gids[v - 1];
    for (int g = prev + 1; g <= cur; ++g) start[g] = v;
}

// ---------------- fused Set2Set (6 iters) + predict MLPs -> out ----------------
// Per-graph independent recurrence: block owns 8 graphs; hs/cs/q_star live in LDS for
// all 6 iterations (no global state round-trips; replaces 13 launches with 1).
// Attention: wave w serves graphs {w, w+4}; single-pass ONLINE softmax over the
// graph's nodes (m,s,acc rescaling) — halves node-loop latency vs two-pass.
#define LS_GPB 8
__global__ __launch_bounds__(256) void k_s2s_final(
    const float* __restrict__ h, const int* __restrict__ segs,
    const float* __restrict__ Wih0, const float* __restrict__ bih0,
    const float* __restrict__ Whh0, const float* __restrict__ bhh0,
    const float* __restrict__ Wih1, const float* __restrict__ bih1,
    const float* __restrict__ Whh1, const float* __restrict__ bhh1,
    const float* __restrict__ Wih2, const float* __restrict__ bih2,
    const float* __restrict__ Whh2, const float* __restrict__ bhh2,
    const float* __restrict__ pW, const float* __restrict__ pb,
    const float* __restrict__ qW1, const float* __restrict__ qb1,
    const float* __restrict__ qW2, const float* __restrict__ qb2,
    const float* __restrict__ qW3, const float* __restrict__ qb3,
    float* __restrict__ out) {
    const int g0 = blockIdx.x * LS_GPB;       // 150 blocks
    const int j = threadIdx.x;                // 0..255
    const int w = j >> 6, lane = j & 63;

    __shared__ float xs[LS_GPB][128];
    __shared__ float hsL[3][LS_GPB][64];
    __shared__ float csL[3][LS_GPB][64];
    __shared__ float gates[LS_GPB][256];
    __shared__ float qst[LS_GPB][128];

    // init state
    for (int idx = j; idx < LS_GPB * 64 * 3; idx += 256) {
        ((float*)hsL)[idx] = 0.f;
        ((float*)csL)[idx] = 0.f;
    }
    for (int idx = j; idx < LS_GPB * 128; idx += 256) ((float*)qst)[idx] = 0.f;
    __syncthreads();

    const float* Wihs[3] = {Wih0, Wih1, Wih2};
    const float* bihs[3] = {bih0, bih1, bih2};
    const float* Whhs[3] = {Whh0, Whh1, Whh2};
    const float* bhhs[3] = {bhh0, bhh1, bhh2};
    const int dins[3] = {128, 64, 64};

    for (int s = 0; s < N_S2S; ++s) {
        // x = q_star
        for (int idx = j; idx < LS_GPB * 128; idx += 256) {
            int n = idx >> 7, d = idx & 127;
            xs[n][d] = qst[n][d];
        }
        __syncthreads();
        // 3-layer LSTM
        for (int l = 0; l < 3; ++l) {
            float acc[LS_GPB];
            float bsum = bihs[l][j] + bhhs[l][j];
            #pragma unroll
            for (int n = 0; n < LS_GPB; ++n) acc[n] = bsum;
            const float* Wih = Wihs[l];
            int din = dins[l];
            for (int i = 0; i < din; ++i) {
                float wv = Wih[i * 256 + j];
                #pragma unroll
                for (int n = 0; n < LS_GPB; ++n) acc[n] = fmaf(xs[n][i], wv, acc[n]);
            }
            const float* Whh = Whhs[l];
            for (int i = 0; i < 64; ++i) {
                float wv = Whh[i * 256 + j];
                #pragma unroll
                for (int n = 0; n < LS_GPB; ++n) acc[n] = fmaf(hsL[l][n][i], wv, acc[n]);
            }
            #pragma unroll
            for (int n = 0; n < LS_GPB; ++n) gates[n][j] = acc[n];
            __syncthreads();
            for (int idx = j; idx < LS_GPB * 64; idx += 256) {
                int n = idx >> 6, d = idx & 63;
                float ig = gates[n][d], fg = gates[n][64 + d];
                float gt = gates[n][128 + d], og = gates[n][192 + d];
                float c = sigmoidf_(fg) * csL[l][n][d] + sigmoidf_(ig) * tanhf_(gt);
                float hnew = sigmoidf_(og) * tanhf_(c);
                csL[l][n][d] = c;
                hsL[l][n][d] = hnew;
                xs[n][d] = hnew;              // input for next layer
            }
            __syncthreads();
        }
        // attention: wave w -> graphs w, w+4 (online softmax; lane = feature d)
        #pragma unroll
        for (int gi = 0; gi < 2; ++gi) {
            int gg = w + gi * 4;
            int g = g0 + gg;
            float qd = xs[gg][lane];          // q for this graph (final LSTM h)
            int vs = segs[g], ve = segs[g + 1];
            float m = -INFINITY, sden = 0.f, accd = 0.f;
            for (int v = vs; v < ve; ++v) {
                float hv = h[(size_t)v * 64 + lane];
                float p = hv * qd;
                #pragma unroll
                for (int off = 32; off > 0; off >>= 1) p += __shfl_xor(p, off, 64);
                float nm = fmaxf(m, p);
                float e1 = __expf(m - nm);    // 0 on first iter (m = -inf)
                float e2 = __expf(p - nm);
                sden = sden * e1 + e2;
                accd = accd * e1 + hv * e2;
                m = nm;
            }
            float r = (ve > vs) ? accd / sden : 0.f;
            qst[gg][lane] = qd;
            qst[gg][64 + lane] = r;
        }
        __syncthreads();
    }

    // predict MLPs: wave w -> graphs w, w+4 (wave-synchronous LDS, no barriers needed)
    #pragma unroll
    for (int gi = 0; gi < 2; ++gi) {
        int gg = w + gi * 4;
        int g = g0 + gg;
        float y = pb[lane];
        for (int i = 0; i < 128; ++i) y = fmaf(qst[gg][i], pW[i * 64 + lane], y);
        y = fmaxf(y, 0.f);
        gates[gg][lane] = y;
        float y1 = qb1[lane];
        for (int i = 0; i < 64; ++i) y1 = fmaf(gates[gg][i], qW1[i * 64 + lane], y1);
        y1 = fmaxf(y1, 0.f);
        gates[gg][64 + lane] = y1;
        float y2 = qb2[lane];
        for (int i = 0; i < 64; ++i) y2 = fmaf(gates[gg][64 + i], qW2[i * 64 + lane], y2);
        y2 = fmaxf(y2, 0.f);
        float p = y2 * qW3[lane];
        #pragma unroll
        for (int off = 32; off > 0; off >>= 1) p += __shfl_xor(p, off, 64);
        if (lane == 0) out[g] = p + qb3[0];
    }
}

extern "C" void kernel_launch(void* const* d_in, const int* in_sizes, int n_in,
                              void* d_out, int out_size, void* d_ws, size_t ws_size,
                              hipStream_t stream) {
    const float* node_feats = (const float*)d_in[0];
    const float* edge_feats = (const float*)d_in[1];
    const int*   src        = (const int*)d_in[2];
    const int*   dst        = (const int*)d_in[3];
    const int*   gids       = (const int*)d_in[4];
    const float* proj_W     = (const float*)d_in[5];
    const float* proj_b     = (const float*)d_in[6];
    const float* eW1        = (const float*)d_in[7];
    const float* eb1        = (const float*)d_in[8];
    const float* eW2        = (const float*)d_in[9];
    const float* eb2        = (const float*)d_in[10];
    const float* conv_b     = (const float*)d_in[11];
    const float* gru_Wih    = (const float*)d_in[12];
    const float* gru_bih    = (const float*)d_in[13];
    const float* gru_Whh    = (const float*)d_in[14];
    const float* gru_bhh    = (const float*)d_in[15];
    const float* pW         = (const float*)d_in[16];
    const float* pb         = (const float*)d_in[17];
    const float* qW1        = (const float*)d_in[18];
    const float* qb1        = (const float*)d_in[19];
    const float* qW2        = (const float*)d_in[20];
    const float* qb2        = (const float*)d_in[21];
    const float* qW3        = (const float*)d_in[22];
    const float* qb3        = (const float*)d_in[23];
    const float* lWih0 = (const float*)d_in[24]; const float* lbih0 = (const float*)d_in[25];
    const float* lWhh0 = (const float*)d_in[26]; const float* lbhh0 = (const float*)d_in[27];
    const float* lWih1 = (const float*)d_in[28]; const float* lbih1 = (const float*)d_in[29];
    const float* lWhh1 = (const float*)d_in[30]; const float* lbhh1 = (const float*)d_in[31];
    const float* lWih2 = (const float*)d_in[32]; const float* lbih2 = (const float*)d_in[33];
    const float* lWhh2 = (const float*)d_in[34]; const float* lbhh2 = (const float*)d_in[35];

    // ---- workspace layout: EXACT round-7 footprint (34,562,756 B, proven to fit).
    // hsbuf/csbuf/qbuf/q_star are no longer used by Set2Set (state lives in LDS);
    // Wcp/bc occupy the hsbuf region permanently now (nothing ever overwrites them).
    char* ws = (char*)d_ws;
    uint16_t* HedgeP = (uint16_t*)(ws + 0);                      // 15,368,192 B (EPAD rows)
    uint16_t* W2p    = (uint16_t*)(ws + 15368192);               //  1,048,576 B
    uint16_t* B2p    = (uint16_t*)(ws + 16416768);               //     16,384 B (real + zero half)
    float*    hcur   = (float*)(ws + 16433152);                  //  7,680,000 B
    float*    agg    = (float*)(ws + 24113152);                  //  7,680,000 B
    int*      segs   = (int*)(ws + 34557952);                    //      4,804 B
    uint16_t* Wcp    = (uint16_t*)(ws + 32407552);               //     65,536 B (hsbuf region)
    float*    bc     = (float*)(ws + 32407552 + 65536);          //      1,024 B

    // --- one-time phase ---
    k_node_proj<<<V / 4, 256, 0, stream>>>(node_feats, proj_W, proj_b, hcur);
    k_edge_hidden<<<EPAD / 8, 256, 0, stream>>>(edge_feats, eW1, eb1, HedgeP);
    k_prep_w2<<<2048, 256, 0, stream>>>(eW2, W2p);
    k_prep_b2<<<32, 256, 0, stream>>>(eb2, B2p);
    k_prep_wc<<<128, 256, 0, stream>>>(gru_Wih, gru_Whh, gru_bih, gru_bhh, Wcp, bc);
    k_seg<<<(V + 1 + 255) / 256, 256, 0, stream>>>(gids, segs);
    // zero agg once (k_gru_mfma re-zeroes it each step after consuming)
    k_zero<<<(480000 + 255) / 256, 256, 0, stream>>>(agg, 480000);  // V*64/4

    // --- message passing ---
    for (int t = 0; t < N_MP; ++t) {
        k_message_mfma<<<NBLK * 2, 256, 0, stream>>>(HedgeP, W2p, B2p, hcur, src, dst, agg);
        k_gru_mfma<<<GRUBLK, 256, 0, stream>>>(agg, conv_b, Wcp, bc, hcur);
    }

    // --- fused Set2Set + predict ---
    k_s2s_final<<<G / LS_GPB, 256, 0, stream>>>(hcur, segs,
        lWih0, lbih0, lWhh0, lbhh0,
        lWih1, lbih1, lWhh1, lbhh1,
        lWih2, lbih2, lWhh2, lbhh2,
        pW, pb, qW1, qb1, qW2, qb2, qW3, qb3,
        (float*)d_out);
}

// Round 13
// 856.966 us; speedup vs baseline: 17.8860x; 1.1132x over previous
//
#include <hip/hip_runtime.h>
#include <stdint.h>
#include <math.h>

#define V 30000
#define E 60000
#define G 1200
#define D 64
#define NODE_IN 74
#define EDGE_IN 12
#define EH 128
#define N_MP 6
#define N_S2S 6

#define NBLK ((E + 63) / 64)   // 938 edge-tiles of 64
#define EPAD (NBLK * 64)       // 60032 padded edge rows
#define GRUBLK ((V + 31) / 32) // 938 node-tiles of 32

typedef short bf16x8 __attribute__((ext_vector_type(8)));
typedef float f32x4 __attribute__((ext_vector_type(4)));

__device__ __forceinline__ float sigmoidf_(float x) {
    return 1.0f / (1.0f + __expf(-x));
}
__device__ __forceinline__ float tanhf_(float x) {
    float t = __expf(-2.0f * fabsf(x));
    float r = (1.0f - t) / (1.0f + t);
    return copysignf(r, x);
}
__device__ __forceinline__ uint16_t f2bf(float f) {
    uint32_t u = __float_as_uint(f);
    u += 0x7fffu + ((u >> 16) & 1u);
    return (uint16_t)(u >> 16);
}
__device__ __forceinline__ float bf2f(uint16_t u) {
    return __uint_as_float(((uint32_t)u) << 16);
}

// ---------------- generic zero-fill ----------------
__global__ void k_zero(float* __restrict__ p, int n4) {
    int i = blockIdx.x * blockDim.x + threadIdx.x;
    if (i < n4) ((float4*)p)[i] = make_float4(0.f, 0.f, 0.f, 0.f);
}

// ---------------- h0 = relu(node_feats @ proj_W + proj_b) ----------------
__global__ void k_node_proj(const float* __restrict__ nf, const float* __restrict__ W,
                            const float* __restrict__ b, float* __restrict__ h) {
    int wave = threadIdx.x >> 6, lane = threadIdx.x & 63;
    int v = blockIdx.x * 4 + wave;           // V % 4 == 0
    __shared__ float xs[4][NODE_IN];
    xs[wave][lane] = nf[(size_t)v * NODE_IN + lane];
    if (lane + 64 < NODE_IN) xs[wave][lane + 64] = nf[(size_t)v * NODE_IN + lane + 64];
    __syncthreads();
    float acc = b[lane];
    #pragma unroll
    for (int i = 0; i < NODE_IN; ++i) acc = fmaf(xs[wave][i], W[i * D + lane], acc);
    h[(size_t)v * D + lane] = fmaxf(acc, 0.0f);
}

// ---------------- HedgeP = bf16-permuted relu(edge_feats @ eW1 + eb1) ----------------
// Layout: chunk(b, w, kt) of 512 elems; elem (quad, m, j) = Hedge[e=b*64+w*16+m][k=kt*32+quad*8+j]
__global__ __launch_bounds__(256) void k_edge_hidden(const float* __restrict__ ef,
                              const float* __restrict__ W1,
                              const float* __restrict__ b1, uint16_t* __restrict__ HedgeP) {
    int blk = blockIdx.x;                     // EPAD/8 = 7504 blocks
    int t = threadIdx.x;
    int half = t >> 7, j = t & 127;
    __shared__ float xs[8][EDGE_IN];
    if (t < 8 * EDGE_IN) {
        int el = t / EDGE_IN, c = t % EDGE_IN;
        int e = blk * 8 + el;
        xs[el][c] = (e < E) ? ef[(size_t)e * EDGE_IN + c] : 0.f;
    }
    __syncthreads();
    #pragma unroll
    for (int l = 0; l < 4; ++l) {
        int el = half * 4 + l;
        int e = blk * 8 + el;
        float acc = b1[j];
        #pragma unroll
        for (int i = 0; i < EDGE_IN; ++i) acc = fmaf(xs[el][i], W1[i * EH + j], acc);
        float r = (e < E) ? fmaxf(acc, 0.0f) : 0.0f;
        int bb = e >> 6, ww = (e >> 4) & 3, m = e & 15;
        int kt = j >> 5, quad = (j >> 3) & 3, jj = j & 7;
        size_t off = ((((size_t)(bb * 4 + ww) * 4 + kt) * 4 + quad) * 16 + m) * 8 + jj;
        HedgeP[off] = f2bf(r);
    }
}

// ---------------- W2p: eW2 (128 x 4096 fp32) -> bf16 B-frag-permuted ----------------
// chunk(i, kt, nt) of 512; elem (quad, n0, j) = eW2[k=kt*32+quad*8+j][i*64+nt*16+n0]
__global__ void k_prep_w2(const float* __restrict__ eW2, uint16_t* __restrict__ W2p) {
    int idx = blockIdx.x * 256 + threadIdx.x;           // 524288 total
    int j = idx & 7;
    int n0 = (idx >> 3) & 15;
    int quad = (idx >> 7) & 3;
    int nt = (idx >> 9) & 3;
    int kt = (idx >> 11) & 3;
    int i = idx >> 13;
    int k = kt * 32 + quad * 8 + j;
    int col = i * 64 + nt * 16 + n0;
    W2p[idx] = f2bf(eW2[(size_t)k * 4096 + col]);
}

// ---------------- B2p: eb2 (4096,) viewed [i][o] -> bf16 B-frag-permuted ----------------
// First 4096 elems = real bias fragments; second 4096 = zeros (used by i-half 1 blocks
// so the bias-init MFMA is branch-free).
__global__ void k_prep_b2(const float* __restrict__ eb2, uint16_t* __restrict__ B2p) {
    int idx = blockIdx.x * 256 + threadIdx.x;           // 8192 total
    if (idx >= 4096) { B2p[idx] = 0; return; }
    int j = idx & 7;
    int n0 = (idx >> 3) & 15;
    int quad = (idx >> 7) & 3;
    int nt = (idx >> 9) & 3;
    int kb = (idx >> 11) & 1;
    B2p[idx] = f2bf(eb2[(size_t)(kb * 32 + quad * 8 + j) * 64 + nt * 16 + n0]);
}

// ---------------- Wcp: GRU combined weight (128 x 256) -> bf16 B-frag-permuted ----------------
// Logical Wc: rows k (0..63 = x via Wih, 64..127 = h via Whh); cols c:
//   c in [0,128):  stacked r,z gates  -> gives ir+hr (c<64) and iz+hz (64<=c<128)
//   c in [128,192): inn only (Wih cols 128..191; h rows zero)
//   c in [192,256): hn  only (Whh cols 128..191; x rows zero)
// chunk (ot*4 + kt) of 512; elem (quad, n0, j) = Wc[k=kt*32+quad*8+j][ot*16+n0]
// Also writes bc[256]: combined gate biases matching the column map.
__global__ void k_prep_wc(const float* __restrict__ Wih, const float* __restrict__ Whh,
                          const float* __restrict__ bih, const float* __restrict__ bhh,
                          uint16_t* __restrict__ Wcp, float* __restrict__ bc) {
    int idx = blockIdx.x * 256 + threadIdx.x;           // 32768 total
    int j = idx & 7;
    int n0 = (idx >> 3) & 15;
    int quad = (idx >> 7) & 3;
    int kt = (idx >> 9) & 3;
    int ot = idx >> 11;                                 // 0..15
    int k = kt * 32 + quad * 8 + j;                     // 0..127
    int c = ot * 16 + n0;                               // 0..255
    float val = 0.f;
    if (c < 128) {
        val = (k < 64) ? Wih[(size_t)k * 192 + c] : Whh[(size_t)(k - 64) * 192 + c];
    } else if (c < 192) {
        if (k < 64) val = Wih[(size_t)k * 192 + c];
    } else {
        if (k >= 64) val = Whh[(size_t)(k - 64) * 192 + (c - 64)];
    }
    Wcp[idx] = f2bf(val);
    if (idx < 256) {
        int d = idx & 63;
        float b;
        if (idx < 64)       b = bih[d] + bhh[d];
        else if (idx < 128) b = bih[64 + d] + bhh[64 + d];
        else if (idx < 192) b = bih[128 + d];
        else                b = bhh[128 + d];
        bc[idx] = b;
    }
}

// ---------------- LSTM packed weights: per-lane float4 gate rows ----------------
// WihP layout: L0 at [0,8192) float4 (din=128), L1 at [8192,12288), L2 at [12288,16384);
//   slot (i,d): float4{W[i][d], W[i][64+d], W[i][128+d], W[i][192+d]}  (i,f,g,o gates)
// WhhP layout: L0 [0,4096), L1 [4096,8192), L2 [8192,12288) — same per-slot packing.
// bc4[l*64+d] = bih_l+bhh_l packed the same way.
__global__ void k_prep_lstm(
    const float* __restrict__ Wih0, const float* __restrict__ bih0,
    const float* __restrict__ Whh0, const float* __restrict__ bhh0,
    const float* __restrict__ Wih1, const float* __restrict__ bih1,
    const float* __restrict__ Whh1, const float* __restrict__ bhh1,
    const float* __restrict__ Wih2, const float* __restrict__ bih2,
    const float* __restrict__ Whh2, const float* __restrict__ bhh2,
    float4* __restrict__ WihP, float4* __restrict__ WhhP, float4* __restrict__ bc4) {
    int idx = blockIdx.x * 256 + threadIdx.x;           // 28864 total slots
    if (idx < 16384) {
        const float* W; int base;
        if (idx < 8192)       { base = 0;     W = Wih0; }
        else if (idx < 12288) { base = 8192;  W = Wih1; }
        else                  { base = 12288; W = Wih2; }
        int local = idx - base;
        int i = local >> 6, d = local & 63;
        WihP[idx] = make_float4(W[(size_t)i * 256 + d],       W[(size_t)i * 256 + 64 + d],
                                W[(size_t)i * 256 + 128 + d], W[(size_t)i * 256 + 192 + d]);
    } else if (idx < 28672) {
        int li = idx - 16384;                           // 0..12287
        int l = li >> 12;
        int local = li & 4095;
        int k = local >> 6, d = local & 63;
        const float* W = (l == 0) ? Whh0 : (l == 1) ? Whh1 : Whh2;
        WhhP[li] = make_float4(W[(size_t)k * 256 + d],       W[(size_t)k * 256 + 64 + d],
                               W[(size_t)k * 256 + 128 + d], W[(size_t)k * 256 + 192 + d]);
    } else if (idx < 28864) {
        int bi = idx - 28672;                           // 0..191
        int l = bi >> 6, d = bi & 63;
        const float* bi_ = (l == 0) ? bih0 : (l == 1) ? bih1 : bih2;
        const float* bh_ = (l == 0) ? bhh0 : (l == 1) ? bhh1 : bhh2;
        bc4[bi] = make_float4(bi_[d] + bh_[d],             bi_[64 + d] + bh_[64 + d],
                              bi_[128 + d] + bh_[128 + d], bi_[192 + d] + bh_[192 + d]);
    }
}

// ---------------- fused We-recompute + message + scatter (EXACT r9 text — PARKED) ----------------
// Grid = 2*NBLK: block bx -> edge-tile b = bx>>1, i-half = bx&1 (i in [32h, 32h+32)).
// Wave w owns output columns [16w, 16w+16). Bias via MFMA against B2p (zeros for half 1).
// DO NOT TOUCH: codegen is bistable. This shape = VGPR 60, Af AGPR-resident, 81 us.
// r10 (LDS anti-remat alias) = neutral; r11 (fp32 HsT epilogue) = scratch-spill blowup.
__global__ __launch_bounds__(256, 3) void k_message_mfma(
    const uint16_t* __restrict__ HedgeP, const uint16_t* __restrict__ W2p,
    const uint16_t* __restrict__ B2p, const float* __restrict__ h,
    const int* __restrict__ src, const int* __restrict__ dst,
    float* __restrict__ agg) {
    const int bx = blockIdx.x;                // 2*938 blocks
    const int b = bx >> 1;
    const int ibase = (bx & 1) * 32;
    const int t = threadIdx.x;
    const int w = t >> 6, lane = t & 63;      // w = this wave's o-tile (nt)
    const int quad = lane >> 4, n0 = lane & 15;

    __shared__ uint16_t HsU[64][72];          // bf16 h rows; 144B stride keeps frags 16B-aligned
    __shared__ int srcv[64], dstv[64];

    if (t < 64) {
        int e = b * 64 + t;
        int sv = 0, dv = -1;
        if (e < E) { sv = src[e]; dv = dst[e]; }
        srcv[t] = sv; dstv[t] = dv;
    }
    __syncthreads();
    for (int idx = t; idx < 4096; idx += 256) {
        int r = idx >> 6, c = idx & 63;
        HsU[r][c] = f2bf(h[(size_t)srcv[r] * 64 + c]);
    }
    // A-fragments: all 4 edge-tiles x 4 K-tiles (same in every wave)
    bf16x8 Af[4][4];
    #pragma unroll
    for (int et = 0; et < 4; ++et)
        #pragma unroll
        for (int kt = 0; kt < 4; ++kt)
            Af[et][kt] = *(const bf16x8*)(HedgeP + (((size_t)(b * 4 + et) * 4 + kt) * 512) + lane * 8);
    __syncthreads();

    // ---- bias init: acc[et] = hA[et] @ b2[:, w-slice]  (zeros for i-half 1) ----
    f32x4 acc[4];
    {
        const uint16_t* b2b = B2p + (size_t)ibase * 128;   // half*4096 elems
        bf16x8 B2f0 = *(const bf16x8*)(b2b + (size_t)(0 * 4 + w) * 512 + lane * 8);
        bf16x8 B2f1 = *(const bf16x8*)(b2b + (size_t)(1 * 4 + w) * 512 + lane * 8);
        #pragma unroll
        for (int et = 0; et < 4; ++et) {
            bf16x8 hA0 = *(const bf16x8*)(&HsU[et * 16 + n0][quad * 8]);
            bf16x8 hA1 = *(const bf16x8*)(&HsU[et * 16 + n0][32 + quad * 8]);
            f32x4 z = {};
            z = __builtin_amdgcn_mfma_f32_16x16x32_bf16(hA0, B2f0, z, 0, 0, 0);
            acc[et] = __builtin_amdgcn_mfma_f32_16x16x32_bf16(hA1, B2f1, z, 0, 0, 0);
        }
    }

    // ---- main loop over this block's 32 i; 4 B-frag loads (own o-slice) per i ----
    for (int ii = 0; ii < 32; ++ii) {
        const int i = ibase + ii;
        const uint16_t* wb = W2p + (size_t)i * 8192 + lane * 8;
        bf16x8 Bf0 = *(const bf16x8*)(wb + (size_t)(0 * 4 + w) * 512);
        bf16x8 Bf1 = *(const bf16x8*)(wb + (size_t)(1 * 4 + w) * 512);
        bf16x8 Bf2 = *(const bf16x8*)(wb + (size_t)(2 * 4 + w) * 512);
        bf16x8 Bf3 = *(const bf16x8*)(wb + (size_t)(3 * 4 + w) * 512);
        #pragma unroll
        for (int et = 0; et < 4; ++et) {
            f32x4 tmp = {};
            tmp = __builtin_amdgcn_mfma_f32_16x16x32_bf16(Af[et][0], Bf0, tmp, 0, 0, 0);
            tmp = __builtin_amdgcn_mfma_f32_16x16x32_bf16(Af[et][1], Bf1, tmp, 0, 0, 0);
            tmp = __builtin_amdgcn_mfma_f32_16x16x32_bf16(Af[et][2], Bf2, tmp, 0, 0, 0);
            tmp = __builtin_amdgcn_mfma_f32_16x16x32_bf16(Af[et][3], Bf3, tmp, 0, 0, 0);
            int r0 = et * 16 + quad * 4;
            acc[et][0] = fmaf(bf2f(HsU[r0 + 0][i]), tmp[0], acc[et][0]);
            acc[et][1] = fmaf(bf2f(HsU[r0 + 1][i]), tmp[1], acc[et][1]);
            acc[et][2] = fmaf(bf2f(HsU[r0 + 2][i]), tmp[2], acc[et][2]);
            acc[et][3] = fmaf(bf2f(HsU[r0 + 3][i]), tmp[3], acc[et][3]);
        }
    }

    // ---- scatter: each wave owns columns w*16..w*16+15 ----
    #pragma unroll
    for (int et = 0; et < 4; ++et) {
        #pragma unroll
        for (int reg = 0; reg < 4; ++reg) {
            int d = dstv[et * 16 + quad * 4 + reg];
            if (d >= 0)
                atomicAdd(agg + (size_t)d * 64 + w * 16 + n0, acc[et][reg]);
        }
    }
}

// ---------------- MFMA GRU: gates = [relu(agg+b)|h] @ Wc; h update; zeroes agg ----------------
// Block = 32 nodes, 4 waves; wave w owns gate columns [64w, 64w+64) (4 o-tiles).
// Gate pre-acts round-trip LDS as bf16; h update reads fp32 hcur (recurrence stays fp32).
__global__ __launch_bounds__(256) void k_gru_mfma(
    float* __restrict__ agg, const float* __restrict__ convb,
    const uint16_t* __restrict__ Wcp, const float* __restrict__ bc,
    float* __restrict__ hcur) {
    const int blk = blockIdx.x;               // GRUBLK = 938
    const int v0 = blk * 32;
    const int t = threadIdx.x;
    const int w = t >> 6, lane = t & 63;
    const int quad = lane >> 4, n0 = lane & 15;

    __shared__ uint16_t As[32][136];          // [x|h] bf16, 272B row stride (16B-aligned frags)
    __shared__ uint16_t Gs[32][264];          // gate pre-acts bf16, 528B stride

    // stage A and zero agg
    for (int idx = t; idx < 2048; idx += 256) {
        int r = idx >> 6, c = idx & 63;
        int v = v0 + r;
        if (v < V) {
            size_t off = (size_t)v * 64 + c;
            float x = fmaxf(agg[off] + convb[c], 0.f);
            agg[off] = 0.f;                   // pre-zero for next step's atomics
            As[r][c] = f2bf(x);
            As[r][64 + c] = f2bf(hcur[off]);
        } else {
            As[r][c] = 0; As[r][64 + c] = 0;
        }
    }
    __syncthreads();

    // A-fragments: 2 row-tiles x 4 K-tiles
    bf16x8 Af[2][4];
    #pragma unroll
    for (int et = 0; et < 2; ++et)
        #pragma unroll
        for (int kt = 0; kt < 4; ++kt)
            Af[et][kt] = *(const bf16x8*)(&As[et * 16 + n0][kt * 32 + quad * 8]);

    // MFMA: wave w's 4 o-tiles (cols 64w..64w+63 of 256)
    f32x4 acc[2][4] = {};
    #pragma unroll
    for (int ot4 = 0; ot4 < 4; ++ot4) {
        const uint16_t* wb = Wcp + (size_t)((w * 4 + ot4) * 4) * 512 + lane * 8;
        bf16x8 B0 = *(const bf16x8*)(wb + 0 * 512);
        bf16x8 B1 = *(const bf16x8*)(wb + 1 * 512);
        bf16x8 B2 = *(const bf16x8*)(wb + 2 * 512);
        bf16x8 B3 = *(const bf16x8*)(wb + 3 * 512);
        #pragma unroll
        for (int et = 0; et < 2; ++et) {
            f32x4 a = acc[et][ot4];
            a = __builtin_amdgcn_mfma_f32_16x16x32_bf16(Af[et][0], B0, a, 0, 0, 0);
            a = __builtin_amdgcn_mfma_f32_16x16x32_bf16(Af[et][1], B1, a, 0, 0, 0);
            a = __builtin_amdgcn_mfma_f32_16x16x32_bf16(Af[et][2], B2, a, 0, 0, 0);
            a = __builtin_amdgcn_mfma_f32_16x16x32_bf16(Af[et][3], B3, a, 0, 0, 0);
            acc[et][ot4] = a;
        }
    }
    // export gates to LDS (C-layout: col=n0, row=quad*4+reg)
    #pragma unroll
    for (int et = 0; et < 2; ++et)
        #pragma unroll
        for (int ot4 = 0; ot4 < 4; ++ot4)
            #pragma unroll
            for (int reg = 0; reg < 4; ++reg)
                Gs[et * 16 + quad * 4 + reg][(w * 4 + ot4) * 16 + n0] = f2bf(acc[et][ot4][reg]);
    __syncthreads();

    // epilogue: per (node, d)
    for (int idx = t; idx < 2048; idx += 256) {
        int r = idx >> 6, d = idx & 63;
        int v = v0 + r;
        if (v >= V) continue;
        size_t off = (size_t)v * 64 + d;
        float rp   = bf2f(Gs[r][d])        + bc[d];
        float zp   = bf2f(Gs[r][64 + d])   + bc[64 + d];
        float innv = bf2f(Gs[r][128 + d])  + bc[128 + d];
        float hnv  = bf2f(Gs[r][192 + d])  + bc[192 + d];
        float hv = hcur[off];
        float rr = sigmoidf_(rp);
        float zz = sigmoidf_(zp);
        float nn = tanhf_(innv + rr * hnv);
        hcur[off] = (1.f - zz) * nn + zz * hv;
    }
}

// ---------------- segment start offsets from sorted gids ----------------
__global__ void k_seg(const int* __restrict__ gids, int* __restrict__ start) {
    int v = blockIdx.x * blockDim.x + threadIdx.x;
    if (v > V) return;
    int cur = (v < V) ? gids[v] : G;
    int prev = (v == 0) ? -1 : gids[v - 1];
    for (int g = prev + 1; g <= cur; ++g) start[g] = v;
}

// ---------------- fused Set2Set (6 iters) + predict MLPs: ONE WAVE PER GRAPH ----------------
// Lane d owns feature d. All LSTM state (h,c per layer), q_star halves live in registers.
// Broadcasts via __shfl with wave-uniform index (v_readlane). ZERO barriers, ZERO LDS.
// Packed float4 gate-rows (WihP/WhhP/bc4) give each lane its 4 gate weights in one load.
__global__ __launch_bounds__(64) void k_s2s_final(
    const float* __restrict__ h, const int* __restrict__ segs,
    const float4* __restrict__ WihP, const float4* __restrict__ WhhP,
    const float4* __restrict__ bc4,
    const float* __restrict__ pW, const float* __restrict__ pb,
    const float* __restrict__ qW1, const float* __restrict__ qb1,
    const float* __restrict__ qW2, const float* __restrict__ qb2,
    const float* __restrict__ qW3, const float* __restrict__ qb3,
    float* __restrict__ out) {
    const int g = blockIdx.x;                 // 1200 single-wave blocks
    const int lane = threadIdx.x;
    const int vs = segs[g], ve = segs[g + 1];

    float h0 = 0.f, c0 = 0.f, h1 = 0.f, c1 = 0.f, h2 = 0.f, c2 = 0.f;
    float qlo = 0.f, qhi = 0.f;               // q_star = [q | readout]
    const float4 b0 = bc4[lane], b1 = bc4[64 + lane], b2 = bc4[128 + lane];
    const float4* Wih1p = WihP + 8192;
    const float4* Wih2p = WihP + 12288;
    const float4* Whh1p = WhhP + 4096;
    const float4* Whh2p = WhhP + 8192;

    for (int s = 0; s < N_S2S; ++s) {
        // ---- layer 0 (x = q_star, din=128) ----
        float4 a = b0;
        #pragma unroll 8
        for (int i = 0; i < 64; ++i) {
            float xv = __shfl(qlo, i, 64);
            float4 wv = WihP[i * 64 + lane];
            a.x = fmaf(xv, wv.x, a.x); a.y = fmaf(xv, wv.y, a.y);
            a.z = fmaf(xv, wv.z, a.z); a.w = fmaf(xv, wv.w, a.w);
        }
        #pragma unroll 8
        for (int i = 0; i < 64; ++i) {
            float xv = __shfl(qhi, i, 64);
            float4 wv = WihP[(64 + i) * 64 + lane];
            a.x = fmaf(xv, wv.x, a.x); a.y = fmaf(xv, wv.y, a.y);
            a.z = fmaf(xv, wv.z, a.z); a.w = fmaf(xv, wv.w, a.w);
        }
        #pragma unroll 8
        for (int k = 0; k < 64; ++k) {
            float hv = __shfl(h0, k, 64);
            float4 wv = WhhP[k * 64 + lane];
            a.x = fmaf(hv, wv.x, a.x); a.y = fmaf(hv, wv.y, a.y);
            a.z = fmaf(hv, wv.z, a.z); a.w = fmaf(hv, wv.w, a.w);
        }
        c0 = sigmoidf_(a.y) * c0 + sigmoidf_(a.x) * tanhf_(a.z);
        h0 = sigmoidf_(a.w) * tanhf_(c0);
        // ---- layer 1 (x = h0) ----
        a = b1;
        #pragma unroll 8
        for (int i = 0; i < 64; ++i) {
            float xv = __shfl(h0, i, 64);
            float4 wv = Wih1p[i * 64 + lane];
            a.x = fmaf(xv, wv.x, a.x); a.y = fmaf(xv, wv.y, a.y);
            a.z = fmaf(xv, wv.z, a.z); a.w = fmaf(xv, wv.w, a.w);
        }
        #pragma unroll 8
        for (int k = 0; k < 64; ++k) {
            float hv = __shfl(h1, k, 64);
            float4 wv = Whh1p[k * 64 + lane];
            a.x = fmaf(hv, wv.x, a.x); a.y = fmaf(hv, wv.y, a.y);
            a.z = fmaf(hv, wv.z, a.z); a.w = fmaf(hv, wv.w, a.w);
        }
        c1 = sigmoidf_(a.y) * c1 + sigmoidf_(a.x) * tanhf_(a.z);
        h1 = sigmoidf_(a.w) * tanhf_(c1);
        // ---- layer 2 (x = h1) ----
        a = b2;
        #pragma unroll 8
        for (int i = 0; i < 64; ++i) {
            float xv = __shfl(h1, i, 64);
            float4 wv = Wih2p[i * 64 + lane];
            a.x = fmaf(xv, wv.x, a.x); a.y = fmaf(xv, wv.y, a.y);
            a.z = fmaf(xv, wv.z, a.z); a.w = fmaf(xv, wv.w, a.w);
        }
        #pragma unroll 8
        for (int k = 0; k < 64; ++k) {
            float hv = __shfl(h2, k, 64);
            float4 wv = Whh2p[k * 64 + lane];
            a.x = fmaf(hv, wv.x, a.x); a.y = fmaf(hv, wv.y, a.y);
            a.z = fmaf(hv, wv.z, a.z); a.w = fmaf(hv, wv.w, a.w);
        }
        c2 = sigmoidf_(a.y) * c2 + sigmoidf_(a.x) * tanhf_(a.z);
        h2 = sigmoidf_(a.w) * tanhf_(c2);
        float qd = h2;
        // ---- attention: online softmax over this graph's nodes (lane = feature) ----
        float m = -INFINITY, sden = 0.f, accd = 0.f;
        for (int v = vs; v < ve; ++v) {
            float hv = h[(size_t)v * 64 + lane];
            float p = hv * qd;
            #pragma unroll
            for (int off = 32; off > 0; off >>= 1) p += __shfl_xor(p, off, 64);
            float nm = fmaxf(m, p);
            float e1 = __expf(m - nm);        // 0 on first iteration (m = -inf)
            float e2 = __expf(p - nm);
            sden = sden * e1 + e2;
            accd = fmaf(hv, e2, accd * e1);
            m = nm;
        }
        qlo = qd;
        qhi = (ve > vs) ? accd / sden : 0.f;
    }

    // ---- predict MLPs (per-wave, register q_star) ----
    float y = pb[lane];
    #pragma unroll 8
    for (int i = 0; i < 64; ++i) y = fmaf(__shfl(qlo, i, 64), pW[i * 64 + lane], y);
    #pragma unroll 8
    for (int i = 0; i < 64; ++i) y = fmaf(__shfl(qhi, i, 64), pW[(64 + i) * 64 + lane], y);
    y = fmaxf(y, 0.f);
    float y1 = qb1[lane];
    #pragma unroll 8
    for (int i = 0; i < 64; ++i) y1 = fmaf(__shfl(y, i, 64), qW1[i * 64 + lane], y1);
    y1 = fmaxf(y1, 0.f);
    float y2 = qb2[lane];
    #pragma unroll 8
    for (int i = 0; i < 64; ++i) y2 = fmaf(__shfl(y1, i, 64), qW2[i * 64 + lane], y2);
    y2 = fmaxf(y2, 0.f);
    float p = y2 * qW3[lane];
    #pragma unroll
    for (int off = 32; off > 0; off >>= 1) p += __shfl_xor(p, off, 64);
    if (lane == 0) out[g] = p + qb3[0];
}

extern "C" void kernel_launch(void* const* d_in, const int* in_sizes, int n_in,
                              void* d_out, int out_size, void* d_ws, size_t ws_size,
                              hipStream_t stream) {
    const float* node_feats = (const float*)d_in[0];
    const float* edge_feats = (const float*)d_in[1];
    const int*   src        = (const int*)d_in[2];
    const int*   dst        = (const int*)d_in[3];
    const int*   gids       = (const int*)d_in[4];
    const float* proj_W     = (const float*)d_in[5];
    const float* proj_b     = (const float*)d_in[6];
    const float* eW1        = (const float*)d_in[7];
    const float* eb1        = (const float*)d_in[8];
    const float* eW2        = (const float*)d_in[9];
    const float* eb2        = (const float*)d_in[10];
    const float* conv_b     = (const float*)d_in[11];
    const float* gru_Wih    = (const float*)d_in[12];
    const float* gru_bih    = (const float*)d_in[13];
    const float* gru_Whh    = (const float*)d_in[14];
    const float* gru_bhh    = (const float*)d_in[15];
    const float* pW         = (const float*)d_in[16];
    const float* pb         = (const float*)d_in[17];
    const float* qW1        = (const float*)d_in[18];
    const float* qb1        = (const float*)d_in[19];
    const float* qW2        = (const float*)d_in[20];
    const float* qb2        = (const float*)d_in[21];
    const float* qW3        = (const float*)d_in[22];
    const float* qb3        = (const float*)d_in[23];
    const float* lWih0 = (const float*)d_in[24]; const float* lbih0 = (const float*)d_in[25];
    const float* lWhh0 = (const float*)d_in[26]; const float* lbhh0 = (const float*)d_in[27];
    const float* lWih1 = (const float*)d_in[28]; const float* lbih1 = (const float*)d_in[29];
    const float* lWhh1 = (const float*)d_in[30]; const float* lbhh1 = (const float*)d_in[31];
    const float* lWih2 = (const float*)d_in[32]; const float* lbih2 = (const float*)d_in[33];
    const float* lWhh2 = (const float*)d_in[34]; const float* lbhh2 = (const float*)d_in[35];

    // ---- workspace layout: within the proven 34,562,756-B footprint.
    // Wcp/bc live in the old hsbuf region; packed LSTM weights in the old csbuf region.
    char* ws = (char*)d_ws;
    uint16_t* HedgeP = (uint16_t*)(ws + 0);                      // 15,368,192 B (EPAD rows)
    uint16_t* W2p    = (uint16_t*)(ws + 15368192);               //  1,048,576 B
    uint16_t* B2p    = (uint16_t*)(ws + 16416768);               //     16,384 B (real + zero half)
    float*    hcur   = (float*)(ws + 16433152);                  //  7,680,000 B
    float*    agg    = (float*)(ws + 24113152);                  //  7,680,000 B
    int*      segs   = (int*)(ws + 34557952);                    //      4,804 B
    uint16_t* Wcp    = (uint16_t*)(ws + 32407552);               //     65,536 B
    float*    bc     = (float*)(ws + 32407552 + 65536);          //      1,024 B
    float4*   WihP   = (float4*)(ws + 33329152);                 //    262,144 B
    float4*   WhhP   = (float4*)(ws + 33591296);                 //    196,608 B
    float4*   bc4    = (float4*)(ws + 33787904);                 //      3,072 B (ends 33,790,976)

    // --- one-time phase ---
    k_node_proj<<<V / 4, 256, 0, stream>>>(node_feats, proj_W, proj_b, hcur);
    k_edge_hidden<<<EPAD / 8, 256, 0, stream>>>(edge_feats, eW1, eb1, HedgeP);
    k_prep_w2<<<2048, 256, 0, stream>>>(eW2, W2p);
    k_prep_b2<<<32, 256, 0, stream>>>(eb2, B2p);
    k_prep_wc<<<128, 256, 0, stream>>>(gru_Wih, gru_Whh, gru_bih, gru_bhh, Wcp, bc);
    k_prep_lstm<<<113, 256, 0, stream>>>(lWih0, lbih0, lWhh0, lbhh0,
                                         lWih1, lbih1, lWhh1, lbhh1,
                                         lWih2, lbih2, lWhh2, lbhh2,
                                         WihP, WhhP, bc4);
    k_seg<<<(V + 1 + 255) / 256, 256, 0, stream>>>(gids, segs);
    // zero agg once (k_gru_mfma re-zeroes it each step after consuming)
    k_zero<<<(480000 + 255) / 256, 256, 0, stream>>>(agg, 480000);  // V*64/4

    // --- message passing ---
    for (int t = 0; t < N_MP; ++t) {
        k_message_mfma<<<NBLK * 2, 256, 0, stream>>>(HedgeP, W2p, B2p, hcur, src, dst, agg);
        k_gru_mfma<<<GRUBLK, 256, 0, stream>>>(agg, conv_b, Wcp, bc, hcur);
    }

    // --- fused Set2Set + predict: one wave per graph ---
    k_s2s_final<<<G, 64, 0, stream>>>(hcur, segs, WihP, WhhP, bc4,
        pW, pb, qW1, qb1, qW2, qb2, qW3, qb3,
        (float*)d_out);
}